// Round 12
// baseline (326.394 us; speedup 1.0000x reference)
//
#include <hip/hip_runtime.h>

#define N_NODES 50000
#define N_EDGES 1600000
#define DIM_IN  512
#define DIM_HID 64
#define DIM_OUT 7
#define NBUCK   196          // ceil(N_NODES/256) dst buckets
#define PART_BLOCKS 256
#define BCAP    16384        // per-bucket ebuf capacity (mean ~8.2K)

using u16 = unsigned short;
using bf16x8 = __attribute__((ext_vector_type(8))) __bf16;
using f32x4  = __attribute__((ext_vector_type(4))) float;

__device__ __forceinline__ float bf2f(u16 u) {
    union { float f; unsigned int i; } v;
    v.i = ((unsigned int)u) << 16;
    return v.f;
}

__device__ __forceinline__ u16 f2bf(float f) {
    union { float f; unsigned int i; } v;
    v.f = f;
    unsigned int r = 0x7FFFu + ((v.i >> 16) & 1u);
    return (u16)((v.i + r) >> 16);
}

__device__ __forceinline__ float bflo(unsigned int u) {
    union { float f; unsigned int i; } v;
    v.i = u << 16;
    return v.f;
}

__device__ __forceinline__ float bfhi(unsigned int u) {
    union { float f; unsigned int i; } v;
    v.i = u & 0xFFFF0000u;
    return v.f;
}

// low-dword load: identical to (int)((long long*)ei)[idx] on little-endian
__device__ __forceinline__ int ld_edge(const int* ei, int i64f, size_t idx) {
    if (i64f) return ei[2 * idx];
    return ei[idx];
}

// ---- W1 transpose + fused input-encoding detection + gcnt zero ----
__launch_bounds__(1024)
__global__ void k_tw1(const u16* __restrict__ xw, const int* __restrict__ ei32,
                      const void* __restrict__ W1, int* __restrict__ flags,
                      int* __restrict__ gcnt, u16* __restrict__ W1T) {
    __shared__ int s1[256];
    __shared__ int s2[256];
    __shared__ int f32s;
    int t = threadIdx.x;
    if (t < 256) {
        u16 w = xw[2 * t];
        int e = (w >> 7) & 0xFF;
        s1[t] = (e >= 100 && e <= 140) ? 1 : 0;
        s2[t] = (ei32[2 * t + 1] != 0) ? 1 : 0;
    }
    __syncthreads();
    for (int off = 128; off >= 1; off >>= 1) {
        if (t < off) { s1[t] += s1[t + off]; s2[t] += s2[t + off]; }
        __syncthreads();
    }
    if (t == 0) f32s = (s1[0] >= 200) ? 0 : 1;
    if (blockIdx.x == 0) {
        if (t == 0) {
            flags[0] = (s1[0] >= 200) ? 0 : 1;
            flags[1] = (s2[0] == 0) ? 1 : 0;
        }
        if (t < NBUCK) gcnt[t] = 0;
    }
    __syncthreads();
    int f32f = f32s;
    int i = blockIdx.x * 1024 + t;          // grid = 32 blocks exactly covers 32768
    if (i < DIM_IN * DIM_HID) {
        int n = i >> 9;
        int k = i & 511;
        if (f32f) W1T[i] = f2bf(((const float*)W1)[k * DIM_HID + n]);
        else      W1T[i] = ((const u16*)W1)[k * DIM_HID + n];
    }
}

// ---- fused count+scatter ----
__launch_bounds__(1024)
__global__ void k_scat(const int* __restrict__ ei, const int* __restrict__ flags,
                       int* __restrict__ gcnt, unsigned int* __restrict__ ebuf) {
    __shared__ int hist[NBUCK];
    __shared__ int cur[NBUCK];
    int t = threadIdx.x, blk = blockIdx.x;
    int i64f = flags[1];
    const int CH = (N_EDGES + PART_BLOCKS - 1) / PART_BLOCKS;  // 6250
    int lo = blk * CH;
    int hi = lo + CH; if (hi > N_EDGES) hi = N_EDGES;
    if (t < NBUCK) hist[t] = 0;
    __syncthreads();
    for (int i = lo + t; i < hi; i += 1024) {
        int s = ld_edge(ei, i64f, (size_t)i);
        int d = ld_edge(ei, i64f, (size_t)N_EDGES + i);
        if ((unsigned)d < (unsigned)N_NODES && (unsigned)s < (unsigned)N_NODES)
            atomicAdd(&hist[d >> 8], 1);
    }
    __syncthreads();
    if (t < NBUCK) {
        int h = hist[t];
        cur[t] = (h > 0) ? atomicAdd(&gcnt[t], h) : 0;
    }
    __syncthreads();
    for (int i = lo + t; i < hi; i += 1024) {
        int s = ld_edge(ei, i64f, (size_t)i);
        int d = ld_edge(ei, i64f, (size_t)N_EDGES + i);
        if ((unsigned)d < (unsigned)N_NODES && (unsigned)s < (unsigned)N_NODES) {
            int b = d >> 8;
            int off = atomicAdd(&cur[b], 1);
            if ((unsigned)off < (unsigned)BCAP)
                ebuf[(size_t)b * BCAP + off] = ((unsigned)s << 8) | (unsigned)(d & 255);
        }
    }
}

// ---- per-bucket: inline bucket prefix scan + LDS degree histogram ->
// rowptr + dinv + compacted CSR col ----
__launch_bounds__(1024)
__global__ void k_cfill(const unsigned int* __restrict__ ebuf,
                        const int* __restrict__ gcnt,
                        int* __restrict__ rowptr, float* __restrict__ dinv,
                        int* __restrict__ col) {
    __shared__ int gs[256];
    __shared__ int dcnt[256];
    __shared__ int sc[256];
    __shared__ int cur[256];
    int b = blockIdx.x, t = threadIdx.x;
    if (t < 256) {
        int gv = (t < NBUCK) ? gcnt[t] : 0;
        if (gv > BCAP) gv = BCAP;
        gs[t] = gv;
    }
    __syncthreads();
    for (int off = 1; off < 256; off <<= 1) {
        int u = (t >= off && t < 256) ? gs[t - off] : 0;
        __syncthreads();
        if (t < 256) gs[t] += u;
        __syncthreads();
    }
    int cntb = gcnt[b]; if (cntb > BCAP) cntb = BCAP;
    int cb = gs[b] - cntb;                 // compacted base of this bucket
    if (b == 0 && t == 0) rowptr[N_NODES] = gs[255];
    const unsigned int* eb = ebuf + (size_t)b * BCAP;

    if (t < 256) dcnt[t] = 0;
    __syncthreads();
    for (int e = t; e < cntb; e += 1024)
        atomicAdd(&dcnt[eb[e] & 255u], 1);
    __syncthreads();
    int v = 0;
    if (t < 256) { v = dcnt[t]; sc[t] = v; }
    __syncthreads();
    for (int off = 1; off < 256; off <<= 1) {
        int u = (t >= off && t < 256) ? sc[t - off] : 0;
        __syncthreads();
        if (t < 256) sc[t] += u;
        __syncthreads();
    }
    if (t < 256) {
        int row0 = cb + sc[t] - v;
        cur[t] = row0;
        int idx = b * 256 + t;
        if (idx < N_NODES) {
            rowptr[idx] = row0;
            dinv[idx] = rsqrtf((float)(v + 1));  // +1 self-loop
        }
    }
    __syncthreads();
    for (int e = t; e < cntb; e += 1024) {
        unsigned int x = eb[e];
        int p = atomicAdd(&cur[x & 255u], 1);
        if ((unsigned)p < (unsigned)N_EDGES) col[p] = (int)(x >> 8);
    }
}

// ---- GEMM1 (MFMA 16x16x32 bf16): hs = bf16((x @ W1) * dinv[row]) ----
// Core = R6 form (simplest of the four equal-performing variants).
// NEW: split-hs store layout -- cols 0-31 to region A [N][32], cols 32-63
// to region B [N][32], so each agg1 half-pass has a 3.2MB (< 4MB/XCD L2)
// gather working set.
__launch_bounds__(256)
__global__ void k_gemm1(const void* __restrict__ xraw, const u16* __restrict__ W1T,
                        const int* __restrict__ flags, const float* __restrict__ dinv,
                        u16* __restrict__ hs) {
    int f32f = flags[0];
    int wave = threadIdx.x >> 6;
    int lane = threadIdx.x & 63;
    int m16 = lane & 15;
    int quad = lane >> 4;
    int rbase = blockIdx.x * 64 + wave * 16;
    int ra = rbase + m16;
    if (ra > N_NODES - 1) ra = N_NODES - 1;
    const u16*   xrow_b = (const u16*)xraw   + (size_t)ra * DIM_IN + quad * 8;
    const float* xrow_f = (const float*)xraw + (size_t)ra * DIM_IN + quad * 8;
    const u16* wrow = W1T + (size_t)m16 * DIM_IN + quad * 8;

    f32x4 acc0 = {0.f, 0.f, 0.f, 0.f};
    f32x4 acc1 = {0.f, 0.f, 0.f, 0.f};
    f32x4 acc2 = {0.f, 0.f, 0.f, 0.f};
    f32x4 acc3 = {0.f, 0.f, 0.f, 0.f};

    for (int ks = 0; ks < DIM_IN / 32; ++ks) {
        bf16x8 a;
        if (f32f) {
            const float4* q = reinterpret_cast<const float4*>(xrow_f + ks * 32);
            float4 p0 = q[0], p1 = q[1];
            union { bf16x8 v; u16 s[8]; } u;
            u.s[0] = f2bf(p0.x); u.s[1] = f2bf(p0.y); u.s[2] = f2bf(p0.z); u.s[3] = f2bf(p0.w);
            u.s[4] = f2bf(p1.x); u.s[5] = f2bf(p1.y); u.s[6] = f2bf(p1.z); u.s[7] = f2bf(p1.w);
            a = u.v;
        } else {
            a = *reinterpret_cast<const bf16x8*>(xrow_b + ks * 32);
        }
        bf16x8 b0 = *reinterpret_cast<const bf16x8*>(wrow + ks * 32);
        bf16x8 b1 = *reinterpret_cast<const bf16x8*>(wrow + ks * 32 + 16 * DIM_IN);
        bf16x8 b2 = *reinterpret_cast<const bf16x8*>(wrow + ks * 32 + 32 * DIM_IN);
        bf16x8 b3 = *reinterpret_cast<const bf16x8*>(wrow + ks * 32 + 48 * DIM_IN);
        acc0 = __builtin_amdgcn_mfma_f32_16x16x32_bf16(a, b0, acc0, 0, 0, 0);
        acc1 = __builtin_amdgcn_mfma_f32_16x16x32_bf16(a, b1, acc1, 0, 0, 0);
        acc2 = __builtin_amdgcn_mfma_f32_16x16x32_bf16(a, b2, acc2, 0, 0, 0);
        acc3 = __builtin_amdgcn_mfma_f32_16x16x32_bf16(a, b3, acc3, 0, 0, 0);
    }

#pragma unroll
    for (int i = 0; i < 4; ++i) {
        int r = rbase + quad * 4 + i;
        if (r < N_NODES) {
            float dv = dinv[r];
            u16* orowA = hs + (size_t)r * 32;                          // cols 0-31
            u16* orowB = hs + (size_t)N_NODES * 32 + (size_t)r * 32;   // cols 32-63
            orowA[ 0 + m16] = f2bf(acc0[i] * dv);
            orowA[16 + m16] = f2bf(acc1[i] * dv);
            orowB[ 0 + m16] = f2bf(acc2[i] * dv);
            orowB[16 + m16] = f2bf(acc3[i] * dv);
        }
    }
}

// ---- layer-1 half-column pull aggregation + GEMM2 partial ----
// Launched twice (half=0: hs region A + W2 rows 0-31 -> pacc;
// half=1: region B + W2 rows 32-63, adds pacc, scales by dinv -> zs).
// Mechanism: each pass's gather working set is 3.2MB < 4MB per-XCD L2
// (R5 counters: unsplit agg1 FETCH=53MB vs 13MB compulsory = L2 thrash).
// The kernel boundary guarantees temporal separation of the two halves.
// Gather: 16 edges/wave-instruction (g=lane>>2 edge slot, q=lane&3 16B
// chunk), 4-deep ILP. Epilogue = proven LDS-transpose + shfl tree.
__launch_bounds__(256)
__global__ void k_agg1h(const u16* __restrict__ hsh, const int* __restrict__ rowptr,
                        const int* __restrict__ col, const float* __restrict__ dinv,
                        const void* __restrict__ b1, const void* __restrict__ W2,
                        const int* __restrict__ flags, int half,
                        float* __restrict__ pacc, float* __restrict__ zs) {
    __shared__ float xh[4][32];
    int f32f = flags[0];
    int wave = threadIdx.x >> 6;
    int lane = threadIdx.x & 63;
    int g = lane >> 2;   // edge slot within 16-edge block
    int q = lane & 3;    // 16B chunk: cols half*32 + q*8 .. +8
    int d = blockIdx.x * 4 + wave;    // grid is exactly N_NODES/4 blocks
    int start = rowptr[d], end = rowptr[d + 1];
    if (start < 0) start = 0;
    if (end > N_EDGES) end = N_EDGES;
    if (end < start) end = start;

    float a[8];
#pragma unroll
    for (int k = 0; k < 8; ++k) a[k] = 0.f;

    const uint4* h4 = reinterpret_cast<const uint4*>(hsh);  // [N][4] uint4
    const int* cp = col + start;
    int ne = end - start;
    int nfull = ne >> 4;

    int it = 0;
    for (; it + 4 <= nfull; it += 4) {
        int c0 = cp[(it + 0) * 16 + g];
        int c1 = cp[(it + 1) * 16 + g];
        int c2 = cp[(it + 2) * 16 + g];
        int c3 = cp[(it + 3) * 16 + g];
        uint4 r0 = h4[(size_t)c0 * 4 + q];
        uint4 r1 = h4[(size_t)c1 * 4 + q];
        uint4 r2 = h4[(size_t)c2 * 4 + q];
        uint4 r3 = h4[(size_t)c3 * 4 + q];
#pragma unroll
        for (int u = 0; u < 4; ++u) {
            uint4 r = (u == 0) ? r0 : (u == 1) ? r1 : (u == 2) ? r2 : r3;
            a[0] += bflo(r.x); a[1] += bfhi(r.x);
            a[2] += bflo(r.y); a[3] += bfhi(r.y);
            a[4] += bflo(r.z); a[5] += bfhi(r.z);
            a[6] += bflo(r.w); a[7] += bfhi(r.w);
        }
    }
    for (; it < nfull; ++it) {
        int c = cp[it * 16 + g];
        uint4 r = h4[(size_t)c * 4 + q];
        a[0] += bflo(r.x); a[1] += bfhi(r.x);
        a[2] += bflo(r.y); a[3] += bfhi(r.y);
        a[4] += bflo(r.z); a[5] += bfhi(r.z);
        a[6] += bflo(r.w); a[7] += bfhi(r.w);
    }
    {
        int e = start + nfull * 16 + g;
        if (e < end) {
            int c = col[e];
            uint4 r = h4[(size_t)c * 4 + q];
            a[0] += bflo(r.x); a[1] += bfhi(r.x);
            a[2] += bflo(r.y); a[3] += bfhi(r.y);
            a[4] += bflo(r.z); a[5] += bfhi(r.z);
            a[6] += bflo(r.w); a[7] += bfhi(r.w);
        }
    }

    // sum the 16 edge-slot groups (lanes differ in bits 2..5)
#pragma unroll
    for (int k = 0; k < 8; ++k) {
        a[k] += __shfl_xor(a[k], 4);
        a[k] += __shfl_xor(a[k], 8);
        a[k] += __shfl_xor(a[k], 16);
        a[k] += __shfl_xor(a[k], 32);
    }

    // self loop (after group-reduce: replicated, not summed)
    {
        uint4 r = h4[(size_t)d * 4 + q];
        a[0] += bflo(r.x); a[1] += bfhi(r.x);
        a[2] += bflo(r.y); a[3] += bfhi(r.y);
        a[4] += bflo(r.z); a[5] += bfhi(r.z);
        a[6] += bflo(r.w); a[7] += bfhi(r.w);
    }

    float dv = dinv[d];
    float h[8];
    int cbase = half * 32 + q * 8;
    if (f32f) {
        const float* bf = (const float*)b1 + cbase;
#pragma unroll
        for (int k = 0; k < 8; ++k) h[k] = fmaxf(a[k] * dv + bf[k], 0.f);
    } else {
        const u16* bb = (const u16*)b1 + cbase;
#pragma unroll
        for (int k = 0; k < 8; ++k) h[k] = fmaxf(a[k] * dv + bf2f(bb[k]), 0.f);
    }

    // transpose chunk layout -> per-column lane layout via LDS
    if (g == 0) {
#pragma unroll
        for (int k = 0; k < 8; ++k) xh[wave][q * 8 + k] = h[k];
    }
    __syncthreads();
    float h2 = (lane < 32) ? xh[wave][lane] : 0.f;
    int wr = half * 32 + (lane & 31);   // W2 row for this lane

    float p[7];
#pragma unroll
    for (int f = 0; f < 7; ++f) {
        float w = f32f ? ((const float*)W2)[wr * DIM_OUT + f]
                       : bf2f(((const u16*)W2)[wr * DIM_OUT + f]);
        p[f] = h2 * w;
    }
#pragma unroll
    for (int off = 32; off >= 1; off >>= 1) {
#pragma unroll
        for (int f = 0; f < 7; ++f) p[f] += __shfl_xor(p[f], off);
    }
    if (lane == 0) {
        if (half == 0) {
#pragma unroll
            for (int f = 0; f < 7; ++f) pacc[(size_t)d * 8 + f] = p[f];
        } else {
#pragma unroll
            for (int f = 0; f < 7; ++f)
                zs[(size_t)d * 8 + f] = (p[f] + pacc[(size_t)d * 8 + f]) * dv;
            zs[(size_t)d * 8 + 7] = 0.f;
        }
    }
}

// ---- layer-2 pull aggregation: out (f32) ----
__launch_bounds__(256)
__global__ void k_agg2(const float* __restrict__ zs, const int* __restrict__ rowptr,
                       const int* __restrict__ col, const float* __restrict__ dinv,
                       const void* __restrict__ b2, const int* __restrict__ flags,
                       float* __restrict__ out) {
    int f32f = flags[0];
    int wave = threadIdx.x >> 6;
    int lane = threadIdx.x & 63;
    int d = blockIdx.x * 4 + wave;
    if (d >= N_NODES) return;
    int f = lane & 7;
    int g = lane >> 3;
    int start = rowptr[d], end = rowptr[d + 1];
    if (start < 0) start = 0;
    if (end > N_EDGES) end = N_EDGES;
    if (end < start) end = start;

    float acc = 0.f;
    for (int base = start; base < end; base += 64) {
        int rem = end - base; if (rem > 64) rem = 64;
        int ce = base + lane;
        int c = (ce < end) ? col[ce] : 0;   // one coalesced load per 64 edges
        float vv[8];
#pragma unroll
        for (int j = 0; j < 8; ++j) {
            int cj = __shfl(c, j * 8 + g);
            vv[j] = (j * 8 + g < rem) ? zs[(size_t)cj * 8 + f] : 0.f;
        }
#pragma unroll
        for (int j = 0; j < 8; ++j) acc += vv[j];
    }

    acc += __shfl_xor(acc, 8);
    acc += __shfl_xor(acc, 16);
    acc += __shfl_xor(acc, 32);

    if (lane < 7) {
        float b2v = f32f ? ((const float*)b2)[lane] : bf2f(((const u16*)b2)[lane]);
        float tot = (acc + zs[(size_t)d * 8 + lane]) * dinv[d] + b2v;
        out[(size_t)d * DIM_OUT + lane] = tot;
    }
}

extern "C" void kernel_launch(void* const* d_in, const int* in_sizes, int n_in,
                              void* d_out, int out_size, void* d_ws, size_t ws_size,
                              hipStream_t stream) {
    const void* x  = d_in[0];
    const int*  ei = (const int*)d_in[1];
    const void* W1 = d_in[2];
    const void* b1 = d_in[3];
    const void* W2 = d_in[4];
    const void* b2 = d_in[5];

    char* ws = (char*)d_ws;
    size_t off = 0;
    auto alloc = [&](size_t bytes) -> void* {
        void* p = ws + off;
        off = (off + bytes + 255) & ~(size_t)255;
        return p;
    };
    int*   flags  = (int*)alloc(32);
    int*   rowptr = (int*)alloc((size_t)(N_NODES + 1) * 4);
    int*   gcnt   = (int*)alloc((size_t)NBUCK * 4);
    float* dinv   = (float*)alloc((size_t)N_NODES * 4);
    u16*   W1T    = (u16*)alloc((size_t)DIM_IN * DIM_HID * 2);
    unsigned int* ebuf = (unsigned int*)alloc((size_t)NBUCK * BCAP * 4);
    int*   colb   = (int*)alloc((size_t)N_EDGES * 4);
    u16*   hs     = (u16*)alloc((size_t)N_NODES * DIM_HID * 2);  // 2x [N][32]
    float* pacc   = (float*)alloc((size_t)N_NODES * 8 * 4);
    float* zs     = (float*)alloc((size_t)N_NODES * 8 * 4);
    float* out    = (float*)d_out;

    u16* hsB = hs + (size_t)N_NODES * 32;

    k_tw1   <<<32, 1024, 0, stream>>>((const u16*)x, ei, W1, flags, gcnt, W1T);
    k_scat  <<<PART_BLOCKS, 1024, 0, stream>>>(ei, flags, gcnt, ebuf);
    k_cfill <<<NBUCK, 1024, 0, stream>>>(ebuf, gcnt, rowptr, dinv, colb);
    k_gemm1 <<<(N_NODES + 63) / 64, 256, 0, stream>>>(x, W1T, flags, dinv, hs);
    k_agg1h <<<(N_NODES + 3) / 4, 256, 0, stream>>>(hs,  rowptr, colb, dinv, b1, W2, flags, 0, pacc, zs);
    k_agg1h <<<(N_NODES + 3) / 4, 256, 0, stream>>>(hsB, rowptr, colb, dinv, b1, W2, flags, 1, pacc, zs);
    k_agg2  <<<(N_NODES + 3) / 4, 256, 0, stream>>>(zs, rowptr, colb, dinv, b2, flags, out);
}

// Round 14
// 301.678 us; speedup vs baseline: 1.0819x; 1.0819x over previous
//
#include <hip/hip_runtime.h>

#define N_NODES 50000
#define N_EDGES 1600000
#define DIM_IN  512
#define DIM_HID 64
#define DIM_OUT 7
#define NBUCK   196          // ceil(N_NODES/256) dst buckets
#define PART_BLOCKS 256
#define BCAP    16384        // per-bucket ebuf capacity (mean ~8.2K)

using u16 = unsigned short;
using bf16x8 = __attribute__((ext_vector_type(8))) __bf16;
using f32x4  = __attribute__((ext_vector_type(4))) float;

__device__ __forceinline__ float bf2f(u16 u) {
    union { float f; unsigned int i; } v;
    v.i = ((unsigned int)u) << 16;
    return v.f;
}

__device__ __forceinline__ u16 f2bf(float f) {
    union { float f; unsigned int i; } v;
    v.f = f;
    unsigned int r = 0x7FFFu + ((v.i >> 16) & 1u);
    return (u16)((v.i + r) >> 16);
}

__device__ __forceinline__ float bflo(unsigned int u) {
    union { float f; unsigned int i; } v;
    v.i = u << 16;
    return v.f;
}

__device__ __forceinline__ float bfhi(unsigned int u) {
    union { float f; unsigned int i; } v;
    v.i = u & 0xFFFF0000u;
    return v.f;
}

// low-dword load: identical to (int)((long long*)ei)[idx] on little-endian
__device__ __forceinline__ int ld_edge(const int* ei, int i64f, size_t idx) {
    if (i64f) return ei[2 * idx];
    return ei[idx];
}

// ---- W1 transpose + fused input-encoding detection + gcnt zero ----
__launch_bounds__(1024)
__global__ void k_tw1(const u16* __restrict__ xw, const int* __restrict__ ei32,
                      const void* __restrict__ W1, int* __restrict__ flags,
                      int* __restrict__ gcnt, u16* __restrict__ W1T) {
    __shared__ int s1[256];
    __shared__ int s2[256];
    __shared__ int f32s;
    int t = threadIdx.x;
    if (t < 256) {
        u16 w = xw[2 * t];
        int e = (w >> 7) & 0xFF;
        s1[t] = (e >= 100 && e <= 140) ? 1 : 0;
        s2[t] = (ei32[2 * t + 1] != 0) ? 1 : 0;
    }
    __syncthreads();
    for (int off = 128; off >= 1; off >>= 1) {
        if (t < off) { s1[t] += s1[t + off]; s2[t] += s2[t + off]; }
        __syncthreads();
    }
    if (t == 0) f32s = (s1[0] >= 200) ? 0 : 1;
    if (blockIdx.x == 0) {
        if (t == 0) {
            flags[0] = (s1[0] >= 200) ? 0 : 1;
            flags[1] = (s2[0] == 0) ? 1 : 0;
        }
        if (t < NBUCK) gcnt[t] = 0;
    }
    __syncthreads();
    int f32f = f32s;
    int i = blockIdx.x * 1024 + t;          // grid = 32 blocks exactly covers 32768
    if (i < DIM_IN * DIM_HID) {
        int n = i >> 9;
        int k = i & 511;
        if (f32f) W1T[i] = f2bf(((const float*)W1)[k * DIM_HID + n]);
        else      W1T[i] = ((const u16*)W1)[k * DIM_HID + n];
    }
}

// ---- fused count+scatter ----
__launch_bounds__(1024)
__global__ void k_scat(const int* __restrict__ ei, const int* __restrict__ flags,
                       int* __restrict__ gcnt, unsigned int* __restrict__ ebuf) {
    __shared__ int hist[NBUCK];
    __shared__ int cur[NBUCK];
    int t = threadIdx.x, blk = blockIdx.x;
    int i64f = flags[1];
    const int CH = (N_EDGES + PART_BLOCKS - 1) / PART_BLOCKS;  // 6250
    int lo = blk * CH;
    int hi = lo + CH; if (hi > N_EDGES) hi = N_EDGES;
    if (t < NBUCK) hist[t] = 0;
    __syncthreads();
    for (int i = lo + t; i < hi; i += 1024) {
        int s = ld_edge(ei, i64f, (size_t)i);
        int d = ld_edge(ei, i64f, (size_t)N_EDGES + i);
        if ((unsigned)d < (unsigned)N_NODES && (unsigned)s < (unsigned)N_NODES)
            atomicAdd(&hist[d >> 8], 1);
    }
    __syncthreads();
    if (t < NBUCK) {
        int h = hist[t];
        cur[t] = (h > 0) ? atomicAdd(&gcnt[t], h) : 0;
    }
    __syncthreads();
    for (int i = lo + t; i < hi; i += 1024) {
        int s = ld_edge(ei, i64f, (size_t)i);
        int d = ld_edge(ei, i64f, (size_t)N_EDGES + i);
        if ((unsigned)d < (unsigned)N_NODES && (unsigned)s < (unsigned)N_NODES) {
            int b = d >> 8;
            int off = atomicAdd(&cur[b], 1);
            if ((unsigned)off < (unsigned)BCAP)
                ebuf[(size_t)b * BCAP + off] = ((unsigned)s << 8) | (unsigned)(d & 255);
        }
    }
}

// ---- per-bucket: inline bucket prefix scan + LDS degree histogram ->
// rowptr + dinv + compacted CSR col ----
__launch_bounds__(1024)
__global__ void k_cfill(const unsigned int* __restrict__ ebuf,
                        const int* __restrict__ gcnt,
                        int* __restrict__ rowptr, float* __restrict__ dinv,
                        int* __restrict__ col) {
    __shared__ int gs[256];
    __shared__ int dcnt[256];
    __shared__ int sc[256];
    __shared__ int cur[256];
    int b = blockIdx.x, t = threadIdx.x;
    if (t < 256) {
        int gv = (t < NBUCK) ? gcnt[t] : 0;
        if (gv > BCAP) gv = BCAP;
        gs[t] = gv;
    }
    __syncthreads();
    for (int off = 1; off < 256; off <<= 1) {
        int u = (t >= off && t < 256) ? gs[t - off] : 0;
        __syncthreads();
        if (t < 256) gs[t] += u;
        __syncthreads();
    }
    int cntb = gcnt[b]; if (cntb > BCAP) cntb = BCAP;
    int cb = gs[b] - cntb;                 // compacted base of this bucket
    if (b == 0 && t == 0) rowptr[N_NODES] = gs[255];
    const unsigned int* eb = ebuf + (size_t)b * BCAP;

    if (t < 256) dcnt[t] = 0;
    __syncthreads();
    for (int e = t; e < cntb; e += 1024)
        atomicAdd(&dcnt[eb[e] & 255u], 1);
    __syncthreads();
    int v = 0;
    if (t < 256) { v = dcnt[t]; sc[t] = v; }
    __syncthreads();
    for (int off = 1; off < 256; off <<= 1) {
        int u = (t >= off && t < 256) ? sc[t - off] : 0;
        __syncthreads();
        if (t < 256) sc[t] += u;
        __syncthreads();
    }
    if (t < 256) {
        int row0 = cb + sc[t] - v;
        cur[t] = row0;
        int idx = b * 256 + t;
        if (idx < N_NODES) {
            rowptr[idx] = row0;
            dinv[idx] = rsqrtf((float)(v + 1));  // +1 self-loop
        }
    }
    __syncthreads();
    for (int e = t; e < cntb; e += 1024) {
        unsigned int x = eb[e];
        int p = atomicAdd(&cur[x & 255u], 1);
        if ((unsigned)p < (unsigned)N_EDGES) col[p] = (int)(x >> 8);
    }
}

// ---- GEMM1 (MFMA 16x16x32 bf16): hs = bf16((x @ W1) * dinv[row]) ----
// R6 form. NOTE (R7-R11): reg-staging, async-LDS staging, launch_bounds,
// and split-K x2 all left this kernel at the same ~58us -- do not re-try
// MLP/occupancy interventions here without new counter evidence.
__launch_bounds__(256)
__global__ void k_gemm1(const void* __restrict__ xraw, const u16* __restrict__ W1T,
                        const int* __restrict__ flags, const float* __restrict__ dinv,
                        u16* __restrict__ hs) {
    int f32f = flags[0];
    int wave = threadIdx.x >> 6;
    int lane = threadIdx.x & 63;
    int m16 = lane & 15;
    int quad = lane >> 4;
    int rbase = blockIdx.x * 64 + wave * 16;
    int ra = rbase + m16;
    if (ra > N_NODES - 1) ra = N_NODES - 1;
    const u16*   xrow_b = (const u16*)xraw   + (size_t)ra * DIM_IN + quad * 8;
    const float* xrow_f = (const float*)xraw + (size_t)ra * DIM_IN + quad * 8;
    const u16* wrow = W1T + (size_t)m16 * DIM_IN + quad * 8;

    f32x4 acc0 = {0.f, 0.f, 0.f, 0.f};
    f32x4 acc1 = {0.f, 0.f, 0.f, 0.f};
    f32x4 acc2 = {0.f, 0.f, 0.f, 0.f};
    f32x4 acc3 = {0.f, 0.f, 0.f, 0.f};

    for (int ks = 0; ks < DIM_IN / 32; ++ks) {
        bf16x8 a;
        if (f32f) {
            const float4* q = reinterpret_cast<const float4*>(xrow_f + ks * 32);
            float4 p0 = q[0], p1 = q[1];
            union { bf16x8 v; u16 s[8]; } u;
            u.s[0] = f2bf(p0.x); u.s[1] = f2bf(p0.y); u.s[2] = f2bf(p0.z); u.s[3] = f2bf(p0.w);
            u.s[4] = f2bf(p1.x); u.s[5] = f2bf(p1.y); u.s[6] = f2bf(p1.z); u.s[7] = f2bf(p1.w);
            a = u.v;
        } else {
            a = *reinterpret_cast<const bf16x8*>(xrow_b + ks * 32);
        }
        bf16x8 b0 = *reinterpret_cast<const bf16x8*>(wrow + ks * 32);
        bf16x8 b1 = *reinterpret_cast<const bf16x8*>(wrow + ks * 32 + 16 * DIM_IN);
        bf16x8 b2 = *reinterpret_cast<const bf16x8*>(wrow + ks * 32 + 32 * DIM_IN);
        bf16x8 b3 = *reinterpret_cast<const bf16x8*>(wrow + ks * 32 + 48 * DIM_IN);
        acc0 = __builtin_amdgcn_mfma_f32_16x16x32_bf16(a, b0, acc0, 0, 0, 0);
        acc1 = __builtin_amdgcn_mfma_f32_16x16x32_bf16(a, b1, acc1, 0, 0, 0);
        acc2 = __builtin_amdgcn_mfma_f32_16x16x32_bf16(a, b2, acc2, 0, 0, 0);
        acc3 = __builtin_amdgcn_mfma_f32_16x16x32_bf16(a, b3, acc3, 0, 0, 0);
    }

#pragma unroll
    for (int i = 0; i < 4; ++i) {
        int r = rbase + quad * 4 + i;
        if (r < N_NODES) {
            float dv = dinv[r];
            u16* orow = hs + (size_t)r * DIM_HID;
            orow[ 0 + m16] = f2bf(acc0[i] * dv);
            orow[16 + m16] = f2bf(acc1[i] * dv);
            orow[32 + m16] = f2bf(acc2[i] * dv);
            orow[48 + m16] = f2bf(acc3[i] * dv);
        }
    }
}

// ---- layer-1 pull aggregation + fused GEMM2 ----
// Gather: dwordx4, lane = (edge-slot g = lane>>3) x (column-octet q = lane&7);
// one wave instruction gathers 8 edge rows; unroll x8 keeps 8 independent
// 1KB gathers in flight (R13: depth 4->8, same lever as the R1->R2 win).
// Epilogue (proven fastest, R2-R4/R6): LDS transpose + 42-shfl tree. The
// per-lane 56-load epilogue (R5) cost +15us; the column-split 2-pass (R12)
// cost +43us -- do not reintroduce either.
__launch_bounds__(256)
__global__ void k_agg1(const u16* __restrict__ hs, const int* __restrict__ rowptr,
                       const int* __restrict__ col, const float* __restrict__ dinv,
                       const void* __restrict__ b1, const void* __restrict__ W2,
                       const int* __restrict__ flags, float* __restrict__ zs) {
    __shared__ float xh[4][64];
    int f32f = flags[0];
    int wave = threadIdx.x >> 6;
    int lane = threadIdx.x & 63;
    int g = lane >> 3;   // edge slot within 8-edge block
    int q = lane & 7;    // column octet: cols q*8 .. q*8+7
    int d = blockIdx.x * 4 + wave;    // grid is exactly N_NODES/4 blocks
    int start = rowptr[d], end = rowptr[d + 1];
    if (start < 0) start = 0;
    if (end > N_EDGES) end = N_EDGES;
    if (end < start) end = start;

    float a[8];
#pragma unroll
    for (int k = 0; k < 8; ++k) a[k] = 0.f;

    const uint4* hs4 = reinterpret_cast<const uint4*>(hs);
    const int* cp = col + start;
    int ne = end - start;
    int nfull = ne >> 3;

    int it = 0;
    for (; it + 8 <= nfull; it += 8) {
        int c[8];
#pragma unroll
        for (int u = 0; u < 8; ++u) c[u] = cp[(it + u) * 8 + g];
        uint4 r[8];
#pragma unroll
        for (int u = 0; u < 8; ++u) r[u] = hs4[(size_t)c[u] * 8 + q];
#pragma unroll
        for (int u = 0; u < 8; ++u) {
            a[0] += bflo(r[u].x); a[1] += bfhi(r[u].x);
            a[2] += bflo(r[u].y); a[3] += bfhi(r[u].y);
            a[4] += bflo(r[u].z); a[5] += bfhi(r[u].z);
            a[6] += bflo(r[u].w); a[7] += bfhi(r[u].w);
        }
    }
    for (; it < nfull; ++it) {
        int c = cp[it * 8 + g];
        uint4 r = hs4[(size_t)c * 8 + q];
        a[0] += bflo(r.x); a[1] += bfhi(r.x);
        a[2] += bflo(r.y); a[3] += bfhi(r.y);
        a[4] += bflo(r.z); a[5] += bfhi(r.z);
        a[6] += bflo(r.w); a[7] += bfhi(r.w);
    }
    {
        int e = start + nfull * 8 + g;
        if (e < end) {
            int c = col[e];
            uint4 r = hs4[(size_t)c * 8 + q];
            a[0] += bflo(r.x); a[1] += bfhi(r.x);
            a[2] += bflo(r.y); a[3] += bfhi(r.y);
            a[4] += bflo(r.z); a[5] += bfhi(r.z);
            a[6] += bflo(r.w); a[7] += bfhi(r.w);
        }
    }

    // sum the 8 edge-slot groups (lanes differ in bits 3..5)
#pragma unroll
    for (int k = 0; k < 8; ++k) {
        a[k] += __shfl_xor(a[k], 8);
        a[k] += __shfl_xor(a[k], 16);
        a[k] += __shfl_xor(a[k], 32);
    }

    // self loop (after group-reduce: replicated, not summed)
    {
        uint4 r = hs4[(size_t)d * 8 + q];
        a[0] += bflo(r.x); a[1] += bfhi(r.x);
        a[2] += bflo(r.y); a[3] += bfhi(r.y);
        a[4] += bflo(r.z); a[5] += bfhi(r.z);
        a[6] += bflo(r.w); a[7] += bfhi(r.w);
    }

    float dv = dinv[d];
    float h[8];
    if (f32f) {
        const float* bf = (const float*)b1 + q * 8;
#pragma unroll
        for (int k = 0; k < 8; ++k) h[k] = fmaxf(a[k] * dv + bf[k], 0.f);
    } else {
        const u16* bb = (const u16*)b1 + q * 8;
#pragma unroll
        for (int k = 0; k < 8; ++k) h[k] = fmaxf(a[k] * dv + bf2f(bb[k]), 0.f);
    }

    // transpose octet layout -> per-column lane layout via LDS
    if (g == 0) {
#pragma unroll
        for (int k = 0; k < 8; ++k) xh[wave][q * 8 + k] = h[k];
    }
    __syncthreads();
    float h2 = xh[wave][lane];

    float p[7];
#pragma unroll
    for (int f = 0; f < 7; ++f) {
        float w = f32f ? ((const float*)W2)[lane * DIM_OUT + f]
                       : bf2f(((const u16*)W2)[lane * DIM_OUT + f]);
        p[f] = h2 * w;
    }
#pragma unroll
    for (int off = 32; off >= 1; off >>= 1) {
#pragma unroll
        for (int f = 0; f < 7; ++f) p[f] += __shfl_xor(p[f], off);
    }
    if (lane == 0) {
#pragma unroll
        for (int f = 0; f < 7; ++f) zs[(size_t)d * 8 + f] = p[f] * dv;
        zs[(size_t)d * 8 + 7] = 0.f;
    }
}

// ---- layer-2 pull aggregation: out (f32) ----
__launch_bounds__(256)
__global__ void k_agg2(const float* __restrict__ zs, const int* __restrict__ rowptr,
                       const int* __restrict__ col, const float* __restrict__ dinv,
                       const void* __restrict__ b2, const int* __restrict__ flags,
                       float* __restrict__ out) {
    int f32f = flags[0];
    int wave = threadIdx.x >> 6;
    int lane = threadIdx.x & 63;
    int d = blockIdx.x * 4 + wave;
    if (d >= N_NODES) return;
    int f = lane & 7;
    int g = lane >> 3;
    int start = rowptr[d], end = rowptr[d + 1];
    if (start < 0) start = 0;
    if (end > N_EDGES) end = N_EDGES;
    if (end < start) end = start;

    float acc = 0.f;
    for (int base = start; base < end; base += 64) {
        int rem = end - base; if (rem > 64) rem = 64;
        int ce = base + lane;
        int c = (ce < end) ? col[ce] : 0;   // one coalesced load per 64 edges
        float vv[8];
#pragma unroll
        for (int j = 0; j < 8; ++j) {
            int cj = __shfl(c, j * 8 + g);
            vv[j] = (j * 8 + g < rem) ? zs[(size_t)cj * 8 + f] : 0.f;
        }
#pragma unroll
        for (int j = 0; j < 8; ++j) acc += vv[j];
    }

    acc += __shfl_xor(acc, 8);
    acc += __shfl_xor(acc, 16);
    acc += __shfl_xor(acc, 32);

    if (lane < 7) {
        float b2v = f32f ? ((const float*)b2)[lane] : bf2f(((const u16*)b2)[lane]);
        float tot = (acc + zs[(size_t)d * 8 + lane]) * dinv[d] + b2v;
        out[(size_t)d * DIM_OUT + lane] = tot;
    }
}

extern "C" void kernel_launch(void* const* d_in, const int* in_sizes, int n_in,
                              void* d_out, int out_size, void* d_ws, size_t ws_size,
                              hipStream_t stream) {
    const void* x  = d_in[0];
    const int*  ei = (const int*)d_in[1];
    const void* W1 = d_in[2];
    const void* b1 = d_in[3];
    const void* W2 = d_in[4];
    const void* b2 = d_in[5];

    char* ws = (char*)d_ws;
    size_t off = 0;
    auto alloc = [&](size_t bytes) -> void* {
        void* p = ws + off;
        off = (off + bytes + 255) & ~(size_t)255;
        return p;
    };
    int*   flags  = (int*)alloc(32);
    int*   rowptr = (int*)alloc((size_t)(N_NODES + 1) * 4);
    int*   gcnt   = (int*)alloc((size_t)NBUCK * 4);
    float* dinv   = (float*)alloc((size_t)N_NODES * 4);
    u16*   W1T    = (u16*)alloc((size_t)DIM_IN * DIM_HID * 2);
    unsigned int* ebuf = (unsigned int*)alloc((size_t)NBUCK * BCAP * 4);
    int*   colb   = (int*)alloc((size_t)N_EDGES * 4);
    u16*   hs     = (u16*)alloc((size_t)N_NODES * DIM_HID * 2);
    float* zs     = (float*)alloc((size_t)N_NODES * 8 * 4);
    float* out    = (float*)d_out;

    k_tw1   <<<32, 1024, 0, stream>>>((const u16*)x, ei, W1, flags, gcnt, W1T);
    k_scat  <<<PART_BLOCKS, 1024, 0, stream>>>(ei, flags, gcnt, ebuf);
    k_cfill <<<NBUCK, 1024, 0, stream>>>(ebuf, gcnt, rowptr, dinv, colb);
    k_gemm1 <<<(N_NODES + 63) / 64, 256, 0, stream>>>(x, W1T, flags, dinv, hs);
    k_agg1  <<<(N_NODES + 3) / 4, 256, 0, stream>>>(hs, rowptr, colb, dinv, b1, W2, flags, zs);
    k_agg2  <<<(N_NODES + 3) / 4, 256, 0, stream>>>(zs, rowptr, colb, dinv, b2, flags, out);
}

// Round 15
// 282.346 us; speedup vs baseline: 1.1560x; 1.0685x over previous
//
#include <hip/hip_runtime.h>

#define N_NODES 50000
#define N_EDGES 1600000
#define DIM_IN  512
#define DIM_HID 64
#define DIM_OUT 7
#define NBUCK   196          // ceil(N_NODES/256) dst buckets
#define PART_BLOCKS 256
#define BCAP    16384        // per-bucket ebuf capacity (mean ~8.2K)

using u16 = unsigned short;
using bf16x8 = __attribute__((ext_vector_type(8))) __bf16;
using f32x4  = __attribute__((ext_vector_type(4))) float;

__device__ __forceinline__ float bf2f(u16 u) {
    union { float f; unsigned int i; } v;
    v.i = ((unsigned int)u) << 16;
    return v.f;
}

__device__ __forceinline__ u16 f2bf(float f) {
    union { float f; unsigned int i; } v;
    v.f = f;
    unsigned int r = 0x7FFFu + ((v.i >> 16) & 1u);
    return (u16)((v.i + r) >> 16);
}

__device__ __forceinline__ float bflo(unsigned int u) {
    union { float f; unsigned int i; } v;
    v.i = u << 16;
    return v.f;
}

__device__ __forceinline__ float bfhi(unsigned int u) {
    union { float f; unsigned int i; } v;
    v.i = u & 0xFFFF0000u;
    return v.f;
}

// async global->LDS, 16B per lane; dest = lds + lane*16 (wave-uniform base)
__device__ __forceinline__ void gload_lds16(const void* g, void* l) {
    __builtin_amdgcn_global_load_lds(
        (const __attribute__((address_space(1))) void*)g,
        (__attribute__((address_space(3))) void*)l, 16, 0, 0);
}

// low-dword load: identical to (int)((long long*)ei)[idx] on little-endian
__device__ __forceinline__ int ld_edge(const int* ei, int i64f, size_t idx) {
    if (i64f) return ei[2 * idx];
    return ei[idx];
}

// ---- W1 transpose + fused input-encoding detection + gcnt zero ----
__launch_bounds__(1024)
__global__ void k_tw1(const u16* __restrict__ xw, const int* __restrict__ ei32,
                      const void* __restrict__ W1, int* __restrict__ flags,
                      int* __restrict__ gcnt, u16* __restrict__ W1T) {
    __shared__ int s1[256];
    __shared__ int s2[256];
    __shared__ int f32s;
    int t = threadIdx.x;
    if (t < 256) {
        u16 w = xw[2 * t];
        int e = (w >> 7) & 0xFF;
        s1[t] = (e >= 100 && e <= 140) ? 1 : 0;
        s2[t] = (ei32[2 * t + 1] != 0) ? 1 : 0;
    }
    __syncthreads();
    for (int off = 128; off >= 1; off >>= 1) {
        if (t < off) { s1[t] += s1[t + off]; s2[t] += s2[t + off]; }
        __syncthreads();
    }
    if (t == 0) f32s = (s1[0] >= 200) ? 0 : 1;
    if (blockIdx.x == 0) {
        if (t == 0) {
            flags[0] = (s1[0] >= 200) ? 0 : 1;
            flags[1] = (s2[0] == 0) ? 1 : 0;
        }
        if (t < NBUCK) gcnt[t] = 0;
    }
    __syncthreads();
    int f32f = f32s;
    int i = blockIdx.x * 1024 + t;          // grid = 32 blocks exactly covers 32768
    if (i < DIM_IN * DIM_HID) {
        int n = i >> 9;
        int k = i & 511;
        if (f32f) W1T[i] = f2bf(((const float*)W1)[k * DIM_HID + n]);
        else      W1T[i] = ((const u16*)W1)[k * DIM_HID + n];
    }
}

// ---- fused count+scatter ----
__launch_bounds__(1024)
__global__ void k_scat(const int* __restrict__ ei, const int* __restrict__ flags,
                       int* __restrict__ gcnt, unsigned int* __restrict__ ebuf) {
    __shared__ int hist[NBUCK];
    __shared__ int cur[NBUCK];
    int t = threadIdx.x, blk = blockIdx.x;
    int i64f = flags[1];
    const int CH = (N_EDGES + PART_BLOCKS - 1) / PART_BLOCKS;  // 6250
    int lo = blk * CH;
    int hi = lo + CH; if (hi > N_EDGES) hi = N_EDGES;
    if (t < NBUCK) hist[t] = 0;
    __syncthreads();
    for (int i = lo + t; i < hi; i += 1024) {
        int s = ld_edge(ei, i64f, (size_t)i);
        int d = ld_edge(ei, i64f, (size_t)N_EDGES + i);
        if ((unsigned)d < (unsigned)N_NODES && (unsigned)s < (unsigned)N_NODES)
            atomicAdd(&hist[d >> 8], 1);
    }
    __syncthreads();
    if (t < NBUCK) {
        int h = hist[t];
        cur[t] = (h > 0) ? atomicAdd(&gcnt[t], h) : 0;
    }
    __syncthreads();
    for (int i = lo + t; i < hi; i += 1024) {
        int s = ld_edge(ei, i64f, (size_t)i);
        int d = ld_edge(ei, i64f, (size_t)N_EDGES + i);
        if ((unsigned)d < (unsigned)N_NODES && (unsigned)s < (unsigned)N_NODES) {
            int b = d >> 8;
            int off = atomicAdd(&cur[b], 1);
            if ((unsigned)off < (unsigned)BCAP)
                ebuf[(size_t)b * BCAP + off] = ((unsigned)s << 8) | (unsigned)(d & 255);
        }
    }
}

// ---- per-bucket: inline bucket prefix scan + LDS degree histogram ->
// rowptr + dinv + compacted CSR col ----
__launch_bounds__(1024)
__global__ void k_cfill(const unsigned int* __restrict__ ebuf,
                        const int* __restrict__ gcnt,
                        int* __restrict__ rowptr, float* __restrict__ dinv,
                        int* __restrict__ col) {
    __shared__ int gs[256];
    __shared__ int dcnt[256];
    __shared__ int sc[256];
    __shared__ int cur[256];
    int b = blockIdx.x, t = threadIdx.x;
    if (t < 256) {
        int gv = (t < NBUCK) ? gcnt[t] : 0;
        if (gv > BCAP) gv = BCAP;
        gs[t] = gv;
    }
    __syncthreads();
    for (int off = 1; off < 256; off <<= 1) {
        int u = (t >= off && t < 256) ? gs[t - off] : 0;
        __syncthreads();
        if (t < 256) gs[t] += u;
        __syncthreads();
    }
    int cntb = gcnt[b]; if (cntb > BCAP) cntb = BCAP;
    int cb = gs[b] - cntb;                 // compacted base of this bucket
    if (b == 0 && t == 0) rowptr[N_NODES] = gs[255];
    const unsigned int* eb = ebuf + (size_t)b * BCAP;

    if (t < 256) dcnt[t] = 0;
    __syncthreads();
    for (int e = t; e < cntb; e += 1024)
        atomicAdd(&dcnt[eb[e] & 255u], 1);
    __syncthreads();
    int v = 0;
    if (t < 256) { v = dcnt[t]; sc[t] = v; }
    __syncthreads();
    for (int off = 1; off < 256; off <<= 1) {
        int u = (t >= off && t < 256) ? sc[t - off] : 0;
        __syncthreads();
        if (t < 256) sc[t] += u;
        __syncthreads();
    }
    if (t < 256) {
        int row0 = cb + sc[t] - v;
        cur[t] = row0;
        int idx = b * 256 + t;
        if (idx < N_NODES) {
            rowptr[idx] = row0;
            dinv[idx] = rsqrtf((float)(v + 1));  // +1 self-loop
        }
    }
    __syncthreads();
    for (int e = t; e < cntb; e += 1024) {
        unsigned int x = eb[e];
        int p = atomicAdd(&cur[x & 255u], 1);
        if ((unsigned)p < (unsigned)N_EDGES) col[p] = (int)(x >> 8);
    }
}

// ---- GEMM1 (MFMA 16x16x32 bf16): hs = bf16((x @ W1) * dinv[row]) ----
// Async-staging form (session-best R10 = 282.65us). bf16 path: 16
// fire-and-forget global_load_lds per wave (zero VGPR cost), one vmcnt(0)
// + sched_barrier(0) fence, MFMA reads A-frags from LDS with matched XOR
// swizzle (rule #21: linear dest + inverse-swizzled global source + same
// XOR on ds_read). NOTE (R7-R11): reg-staging, launch_bounds, split-K all
// measured identical (~58us) -- this kernel is at a latency floor invariant
// to MLP/occupancy interventions.
__launch_bounds__(256)
__global__ void k_gemm1(const void* __restrict__ xraw, const u16* __restrict__ W1T,
                        const int* __restrict__ flags, const float* __restrict__ dinv,
                        u16* __restrict__ hs) {
    __shared__ u16 xs[64][512];   // 64KB -> 2 blocks/CU
    int f32f = flags[0];
    int wave = threadIdx.x >> 6;
    int lane = threadIdx.x & 63;
    int m16 = lane & 15;
    int quad = lane >> 4;
    int rbase = blockIdx.x * 64 + wave * 16;
    const u16* wrow = W1T + (size_t)m16 * DIM_IN + quad * 8;

    f32x4 acc0 = {0.f, 0.f, 0.f, 0.f};
    f32x4 acc1 = {0.f, 0.f, 0.f, 0.f};
    f32x4 acc2 = {0.f, 0.f, 0.f, 0.f};
    f32x4 acc3 = {0.f, 0.f, 0.f, 0.f};

    if (!f32f) {
        // ---- stage this wave's 16 rows into LDS, swizzled source ----
        const char* xb = (const char*)xraw;
#pragma unroll
        for (int rr = 0; rr < 16; ++rr) {
            int r = rbase + rr; if (r > N_NODES - 1) r = N_NODES - 1;
            const char* src = xb + (size_t)r * 1024 + ((lane * 16) ^ ((r & 7) << 4));
            gload_lds16(src, &xs[wave * 16 + rr][0]);
        }
        asm volatile("s_waitcnt vmcnt(0)" ::: "memory");
        __builtin_amdgcn_sched_barrier(0);   // rule #18 fence: nothing crosses the wait

        int rrd = rbase + m16; if (rrd > N_NODES - 1) rrd = N_NODES - 1;
        const char* arow = (const char*)&xs[wave * 16 + m16][0];
        int sw = (rrd & 7) << 4;
#pragma unroll
        for (int ks = 0; ks < 16; ++ks) {
            bf16x8 a = *reinterpret_cast<const bf16x8*>(
                arow + ((ks * 64 + quad * 16) ^ sw));
            bf16x8 b0 = *reinterpret_cast<const bf16x8*>(wrow + ks * 32);
            bf16x8 b1 = *reinterpret_cast<const bf16x8*>(wrow + ks * 32 + 16 * DIM_IN);
            bf16x8 b2 = *reinterpret_cast<const bf16x8*>(wrow + ks * 32 + 32 * DIM_IN);
            bf16x8 b3 = *reinterpret_cast<const bf16x8*>(wrow + ks * 32 + 48 * DIM_IN);
            acc0 = __builtin_amdgcn_mfma_f32_16x16x32_bf16(a, b0, acc0, 0, 0, 0);
            acc1 = __builtin_amdgcn_mfma_f32_16x16x32_bf16(a, b1, acc1, 0, 0, 0);
            acc2 = __builtin_amdgcn_mfma_f32_16x16x32_bf16(a, b2, acc2, 0, 0, 0);
            acc3 = __builtin_amdgcn_mfma_f32_16x16x32_bf16(a, b3, acc3, 0, 0, 0);
        }
    } else {
        // f32 input fallback (unused in this harness): simple rolled loop
        int ra = rbase + m16; if (ra > N_NODES - 1) ra = N_NODES - 1;
        const float* xrow_f = (const float*)xraw + (size_t)ra * DIM_IN + quad * 8;
        for (int ks = 0; ks < 16; ++ks) {
            const float4* qq = reinterpret_cast<const float4*>(xrow_f + ks * 32);
            float4 p0 = qq[0], p1 = qq[1];
            union { bf16x8 v; u16 s[8]; } u;
            u.s[0] = f2bf(p0.x); u.s[1] = f2bf(p0.y); u.s[2] = f2bf(p0.z); u.s[3] = f2bf(p0.w);
            u.s[4] = f2bf(p1.x); u.s[5] = f2bf(p1.y); u.s[6] = f2bf(p1.z); u.s[7] = f2bf(p1.w);
            bf16x8 a = u.v;
            bf16x8 b0 = *reinterpret_cast<const bf16x8*>(wrow + ks * 32);
            bf16x8 b1 = *reinterpret_cast<const bf16x8*>(wrow + ks * 32 + 16 * DIM_IN);
            bf16x8 b2 = *reinterpret_cast<const bf16x8*>(wrow + ks * 32 + 32 * DIM_IN);
            bf16x8 b3 = *reinterpret_cast<const bf16x8*>(wrow + ks * 32 + 48 * DIM_IN);
            acc0 = __builtin_amdgcn_mfma_f32_16x16x32_bf16(a, b0, acc0, 0, 0, 0);
            acc1 = __builtin_amdgcn_mfma_f32_16x16x32_bf16(a, b1, acc1, 0, 0, 0);
            acc2 = __builtin_amdgcn_mfma_f32_16x16x32_bf16(a, b2, acc2, 0, 0, 0);
            acc3 = __builtin_amdgcn_mfma_f32_16x16x32_bf16(a, b3, acc3, 0, 0, 0);
        }
    }

#pragma unroll
    for (int i = 0; i < 4; ++i) {
        int r = rbase + quad * 4 + i;
        if (r < N_NODES) {
            float dv = dinv[r];
            u16* orow = hs + (size_t)r * DIM_HID;
            orow[ 0 + m16] = f2bf(acc0[i] * dv);
            orow[16 + m16] = f2bf(acc1[i] * dv);
            orow[32 + m16] = f2bf(acc2[i] * dv);
            orow[48 + m16] = f2bf(acc3[i] * dv);
        }
    }
}

// ---- layer-1 pull aggregation + fused GEMM2 ----
// Gather: dwordx4, lane = (edge-slot g = lane>>3) x (column-octet q = lane&7);
// one wave instruction gathers 8 edge rows, unroll x4 keeps 4 in flight.
// Depth 4 is the measured optimum: depth 8 (R14) cost +15us (occupancy
// 71->49%, VALUBusy down). Epilogue (proven fastest, R2-R4/R6): LDS
// transpose + 42-shfl tree. Per-lane 56-load epilogue (R5) +15us;
// column-split 2-pass (R12) +43us -- do not reintroduce any of these.
__launch_bounds__(256)
__global__ void k_agg1(const u16* __restrict__ hs, const int* __restrict__ rowptr,
                       const int* __restrict__ col, const float* __restrict__ dinv,
                       const void* __restrict__ b1, const void* __restrict__ W2,
                       const int* __restrict__ flags, float* __restrict__ zs) {
    __shared__ float xh[4][64];
    int f32f = flags[0];
    int wave = threadIdx.x >> 6;
    int lane = threadIdx.x & 63;
    int g = lane >> 3;   // edge slot within 8-edge block
    int q = lane & 7;    // column octet: cols q*8 .. q*8+7
    int d = blockIdx.x * 4 + wave;    // grid is exactly N_NODES/4 blocks
    int start = rowptr[d], end = rowptr[d + 1];
    if (start < 0) start = 0;
    if (end > N_EDGES) end = N_EDGES;
    if (end < start) end = start;

    float a[8];
#pragma unroll
    for (int k = 0; k < 8; ++k) a[k] = 0.f;

    const uint4* hs4 = reinterpret_cast<const uint4*>(hs);
    const int* cp = col + start;
    int ne = end - start;
    int nfull = ne >> 3;

    int it = 0;
    for (; it + 4 <= nfull; it += 4) {
        int c0 = cp[(it + 0) * 8 + g];
        int c1 = cp[(it + 1) * 8 + g];
        int c2 = cp[(it + 2) * 8 + g];
        int c3 = cp[(it + 3) * 8 + g];
        uint4 r0 = hs4[(size_t)c0 * 8 + q];
        uint4 r1 = hs4[(size_t)c1 * 8 + q];
        uint4 r2 = hs4[(size_t)c2 * 8 + q];
        uint4 r3 = hs4[(size_t)c3 * 8 + q];
#pragma unroll
        for (int u = 0; u < 4; ++u) {
            uint4 r = (u == 0) ? r0 : (u == 1) ? r1 : (u == 2) ? r2 : r3;
            a[0] += bflo(r.x); a[1] += bfhi(r.x);
            a[2] += bflo(r.y); a[3] += bfhi(r.y);
            a[4] += bflo(r.z); a[5] += bfhi(r.z);
            a[6] += bflo(r.w); a[7] += bfhi(r.w);
        }
    }
    for (; it < nfull; ++it) {
        int c = cp[it * 8 + g];
        uint4 r = hs4[(size_t)c * 8 + q];
        a[0] += bflo(r.x); a[1] += bfhi(r.x);
        a[2] += bflo(r.y); a[3] += bfhi(r.y);
        a[4] += bflo(r.z); a[5] += bfhi(r.z);
        a[6] += bflo(r.w); a[7] += bfhi(r.w);
    }
    {
        int e = start + nfull * 8 + g;
        if (e < end) {
            int c = col[e];
            uint4 r = hs4[(size_t)c * 8 + q];
            a[0] += bflo(r.x); a[1] += bfhi(r.x);
            a[2] += bflo(r.y); a[3] += bfhi(r.y);
            a[4] += bflo(r.z); a[5] += bfhi(r.z);
            a[6] += bflo(r.w); a[7] += bfhi(r.w);
        }
    }

    // sum the 8 edge-slot groups (lanes differ in bits 3..5)
#pragma unroll
    for (int k = 0; k < 8; ++k) {
        a[k] += __shfl_xor(a[k], 8);
        a[k] += __shfl_xor(a[k], 16);
        a[k] += __shfl_xor(a[k], 32);
    }

    // self loop (after group-reduce: replicated, not summed)
    {
        uint4 r = hs4[(size_t)d * 8 + q];
        a[0] += bflo(r.x); a[1] += bfhi(r.x);
        a[2] += bflo(r.y); a[3] += bfhi(r.y);
        a[4] += bflo(r.z); a[5] += bfhi(r.z);
        a[6] += bflo(r.w); a[7] += bfhi(r.w);
    }

    float dv = dinv[d];
    float h[8];
    if (f32f) {
        const float* bf = (const float*)b1 + q * 8;
#pragma unroll
        for (int k = 0; k < 8; ++k) h[k] = fmaxf(a[k] * dv + bf[k], 0.f);
    } else {
        const u16* bb = (const u16*)b1 + q * 8;
#pragma unroll
        for (int k = 0; k < 8; ++k) h[k] = fmaxf(a[k] * dv + bf2f(bb[k]), 0.f);
    }

    // transpose octet layout -> per-column lane layout via LDS
    if (g == 0) {
#pragma unroll
        for (int k = 0; k < 8; ++k) xh[wave][q * 8 + k] = h[k];
    }
    __syncthreads();
    float h2 = xh[wave][lane];

    float p[7];
#pragma unroll
    for (int f = 0; f < 7; ++f) {
        float w = f32f ? ((const float*)W2)[lane * DIM_OUT + f]
                       : bf2f(((const u16*)W2)[lane * DIM_OUT + f]);
        p[f] = h2 * w;
    }
#pragma unroll
    for (int off = 32; off >= 1; off >>= 1) {
#pragma unroll
        for (int f = 0; f < 7; ++f) p[f] += __shfl_xor(p[f], off);
    }
    if (lane == 0) {
#pragma unroll
        for (int f = 0; f < 7; ++f) zs[(size_t)d * 8 + f] = p[f] * dv;
        zs[(size_t)d * 8 + 7] = 0.f;
    }
}

// ---- layer-2 pull aggregation: out (f32) ----
__launch_bounds__(256)
__global__ void k_agg2(const float* __restrict__ zs, const int* __restrict__ rowptr,
                       const int* __restrict__ col, const float* __restrict__ dinv,
                       const void* __restrict__ b2, const int* __restrict__ flags,
                       float* __restrict__ out) {
    int f32f = flags[0];
    int wave = threadIdx.x >> 6;
    int lane = threadIdx.x & 63;
    int d = blockIdx.x * 4 + wave;
    if (d >= N_NODES) return;
    int f = lane & 7;
    int g = lane >> 3;
    int start = rowptr[d], end = rowptr[d + 1];
    if (start < 0) start = 0;
    if (end > N_EDGES) end = N_EDGES;
    if (end < start) end = start;

    float acc = 0.f;
    for (int base = start; base < end; base += 64) {
        int rem = end - base; if (rem > 64) rem = 64;
        int ce = base + lane;
        int c = (ce < end) ? col[ce] : 0;   // one coalesced load per 64 edges
        float vv[8];
#pragma unroll
        for (int j = 0; j < 8; ++j) {
            int cj = __shfl(c, j * 8 + g);
            vv[j] = (j * 8 + g < rem) ? zs[(size_t)cj * 8 + f] : 0.f;
        }
#pragma unroll
        for (int j = 0; j < 8; ++j) acc += vv[j];
    }

    acc += __shfl_xor(acc, 8);
    acc += __shfl_xor(acc, 16);
    acc += __shfl_xor(acc, 32);

    if (lane < 7) {
        float b2v = f32f ? ((const float*)b2)[lane] : bf2f(((const u16*)b2)[lane]);
        float tot = (acc + zs[(size_t)d * 8 + lane]) * dinv[d] + b2v;
        out[(size_t)d * DIM_OUT + lane] = tot;
    }
}

extern "C" void kernel_launch(void* const* d_in, const int* in_sizes, int n_in,
                              void* d_out, int out_size, void* d_ws, size_t ws_size,
                              hipStream_t stream) {
    const void* x  = d_in[0];
    const int*  ei = (const int*)d_in[1];
    const void* W1 = d_in[2];
    const void* b1 = d_in[3];
    const void* W2 = d_in[4];
    const void* b2 = d_in[5];

    char* ws = (char*)d_ws;
    size_t off = 0;
    auto alloc = [&](size_t bytes) -> void* {
        void* p = ws + off;
        off = (off + bytes + 255) & ~(size_t)255;
        return p;
    };
    int*   flags  = (int*)alloc(32);
    int*   rowptr = (int*)alloc((size_t)(N_NODES + 1) * 4);
    int*   gcnt   = (int*)alloc((size_t)NBUCK * 4);
    float* dinv   = (float*)alloc((size_t)N_NODES * 4);
    u16*   W1T    = (u16*)alloc((size_t)DIM_IN * DIM_HID * 2);
    unsigned int* ebuf = (unsigned int*)alloc((size_t)NBUCK * BCAP * 4);
    int*   colb   = (int*)alloc((size_t)N_EDGES * 4);
    u16*   hs     = (u16*)alloc((size_t)N_NODES * DIM_HID * 2);
    float* zs     = (float*)alloc((size_t)N_NODES * 8 * 4);
    float* out    = (float*)d_out;

    k_tw1   <<<32, 1024, 0, stream>>>((const u16*)x, ei, W1, flags, gcnt, W1T);
    k_scat  <<<PART_BLOCKS, 1024, 0, stream>>>(ei, flags, gcnt, ebuf);
    k_cfill <<<NBUCK, 1024, 0, stream>>>(ebuf, gcnt, rowptr, dinv, colb);
    k_gemm1 <<<(N_NODES + 63) / 64, 256, 0, stream>>>(x, W1T, flags, dinv, hs);
    k_agg1  <<<(N_NODES + 3) / 4, 256, 0, stream>>>(hs, rowptr, colb, dinv, b1, W2, flags, zs);
    k_agg2  <<<(N_NODES + 3) / 4, 256, 0, stream>>>(zs, rowptr, colb, dinv, b2, flags, out);
}